// Round 15
// baseline (642.555 us; speedup 1.0000x reference)
//
#include <hip/hip_runtime.h>
#include <hip/hip_bf16.h>
#include <hip/hip_fp16.h>
#include <hip/hip_cooperative_groups.h>

namespace cg = cooperative_groups;

#define N_NODES 50000
#define N_EDGES 1600000
#define N_GRAPHS 64
#define G1BLKS 1563            // ceil(N_NODES/32) gemm1 blocks in mega kernel
#define NSH 8                  // histogram shards
#define SH_STRIDE 50048        // per-shard stride (≥ N_NODES, 64B aligned)
#define NBLK8 6250             // ceil(N_NODES/8) node-blocks for agg
#define COOP_BLKS 1024

// ---------- helpers ----------
__device__ __forceinline__ float coef_of(unsigned p) {
    return __half2float(__ushort_as_half((unsigned short)(p & 0xFFFFu)));
}

// ---------- MEGA: blocks [0,G1BLKS) = gemm1 (raw f16 out); rest = sharded packed hist ----------
__global__ void mega1(const float* __restrict__ X, const float* __restrict__ W,
                      __half* __restrict__ Yh, const int* __restrict__ dst,
                      const float* __restrict__ ew,
                      unsigned long long* __restrict__ packed8,
                      unsigned short* __restrict__ pos16) {
    __shared__ float Xl[32][132];
    if (blockIdx.x >= G1BLKS) {
        const int sh = blockIdx.x & (NSH - 1);
        unsigned long long* __restrict__ pk = packed8 + (size_t)sh * SH_STRIDE;
        int e = (blockIdx.x - G1BLKS) * 256 + threadIdx.x;
        if (e < N_EDGES) {
            int d = __builtin_nontemporal_load(&dst[e]);
            float w = __builtin_nontemporal_load(&ew[e]);
            unsigned fix = (unsigned)(w * 16777216.0f);
            unsigned long long old = atomicAdd(&pk[d], 0x100000000ull | (unsigned long long)fix);
            pos16[e] = (unsigned short)((sh << 12) | (unsigned)(old >> 32));
        }
        return;
    }
    const int rt = threadIdx.x >> 5;
    const int ct = threadIdx.x & 31;
    const int base = blockIdx.x * 32;
    for (int i = threadIdx.x; i < 32 * 32; i += 256) {
        int rr = i >> 5, cc = (i & 31) << 2;
        int gr = base + rr;
        float4 v = (gr < N_NODES) ? *(const float4*)&X[(size_t)gr * 128 + cc]
                                  : make_float4(0.f, 0.f, 0.f, 0.f);
        Xl[rr][cc] = v.x; Xl[rr][cc + 1] = v.y; Xl[rr][cc + 2] = v.z; Xl[rr][cc + 3] = v.w;
    }
    __syncthreads();
    float acc[4][4] = {};
    for (int k = 0; k < 128; k += 4) {
        float4 a0 = *(const float4*)&Xl[rt * 4 + 0][k];
        float4 a1 = *(const float4*)&Xl[rt * 4 + 1][k];
        float4 a2 = *(const float4*)&Xl[rt * 4 + 2][k];
        float4 a3 = *(const float4*)&Xl[rt * 4 + 3][k];
        float4 w0 = *(const float4*)&W[(size_t)(k + 0) * 128 + ct * 4];
        float4 w1 = *(const float4*)&W[(size_t)(k + 1) * 128 + ct * 4];
        float4 w2 = *(const float4*)&W[(size_t)(k + 2) * 128 + ct * 4];
        float4 w3 = *(const float4*)&W[(size_t)(k + 3) * 128 + ct * 4];
        #define STEP(av, wv)  \
            acc[0][0] += av##0 * wv.x; acc[0][1] += av##0 * wv.y; acc[0][2] += av##0 * wv.z; acc[0][3] += av##0 * wv.w; \
            acc[1][0] += av##1 * wv.x; acc[1][1] += av##1 * wv.y; acc[1][2] += av##1 * wv.z; acc[1][3] += av##1 * wv.w; \
            acc[2][0] += av##2 * wv.x; acc[2][1] += av##2 * wv.y; acc[2][2] += av##2 * wv.z; acc[2][3] += av##2 * wv.w; \
            acc[3][0] += av##3 * wv.x; acc[3][1] += av##3 * wv.y; acc[3][2] += av##3 * wv.z; acc[3][3] += av##3 * wv.w;
        { float ax0=a0.x, ax1=a1.x, ax2=a2.x, ax3=a3.x; STEP(ax, w0) }
        { float ay0=a0.y, ay1=a1.y, ay2=a2.y, ay3=a3.y; STEP(ay, w1) }
        { float az0=a0.z, az1=a1.z, az2=a2.z, az3=a3.z; STEP(az, w2) }
        { float aw0=a0.w, aw1=a1.w, aw2=a2.w, aw3=a3.w; STEP(aw, w3) }
        #undef STEP
    }
    const int pc = ct >> 3;
    const int cw = (ct & 7) * 4;
    for (int i = 0; i < 4; ++i) {
        int gr = base + rt * 4 + i;
        if (gr < N_NODES) {
            ushort4 u;
            u.x = __half_as_ushort(__float2half(acc[i][0]));
            u.y = __half_as_ushort(__float2half(acc[i][1]));
            u.z = __half_as_ushort(__float2half(acc[i][2]));
            u.w = __half_as_ushort(__float2half(acc[i][3]));
            *(ushort4*)&Yh[((size_t)pc * N_NODES + gr) * 32 + cw] = u;
        }
    }
}

// ---------- cooperative CSR finish: dinv+bsum -> boff -> row_start+soff -> fill ----------
__global__ void csr_build_coop(const unsigned long long* __restrict__ packed8,
                               const int* __restrict__ src, const int* __restrict__ dst,
                               const float* __restrict__ ew,
                               const unsigned short* __restrict__ pos16,
                               int* __restrict__ bsum, int* __restrict__ boff,
                               int* __restrict__ row_start, int* __restrict__ soff,
                               float* __restrict__ dinv, unsigned* __restrict__ csr,
                               float* __restrict__ den_pool) {
    cg::grid_group grid = cg::this_grid();
    __shared__ int s[256];
    const int tid = blockIdx.x * 256 + threadIdx.x;

    // ---- phase A: shard totals -> dinv, per-block count sums; zero den+pooled ----
    int c = 0;
    if (tid < N_NODES) {
        unsigned long long csum = 0, fsum = 0;
        #pragma unroll
        for (int sh = 0; sh < NSH; ++sh) {
            unsigned long long p = packed8[(size_t)sh * SH_STRIDE + tid];
            csum += p >> 32;
            fsum += p & 0xFFFFFFFFull;
        }
        c = (int)csum;
        dinv[tid] = rsqrtf((float)fsum * (1.0f / 16777216.0f) + 1.0f);
    }
    if (tid < 64 + 4096) den_pool[tid] = 0.f;
    if (blockIdx.x < 196) {
        s[threadIdx.x] = c;
        __syncthreads();
        for (int o = 128; o; o >>= 1) {
            if (threadIdx.x < o) s[threadIdx.x] += s[threadIdx.x + o];
            __syncthreads();
        }
        if (threadIdx.x == 0) bsum[blockIdx.x] = s[0];
    }
    grid.sync();

    // ---- phase B: block 0 scans bsum[196] -> boff (exclusive) ----
    if (blockIdx.x == 0) {
        int v = (threadIdx.x < 196) ? bsum[threadIdx.x] : 0;
        s[threadIdx.x] = v;
        __syncthreads();
        for (int o = 1; o < 256; o <<= 1) {
            int t = 0;
            if (threadIdx.x >= o) t = s[threadIdx.x - o];
            __syncthreads();
            s[threadIdx.x] += t;
            __syncthreads();
        }
        if (threadIdx.x < 196) boff[threadIdx.x] = s[threadIdx.x] - v;
        if (threadIdx.x == 0) row_start[N_NODES] = N_EDGES;
    }
    grid.sync();

    // ---- phase C: per-node scan -> row_start + per-shard soff ----
    if (blockIdx.x < 196) {
        int idx = tid;
        int cs[NSH];
        int v = 0;
        if (idx < N_NODES) {
            #pragma unroll
            for (int sh = 0; sh < NSH; ++sh) {
                cs[sh] = (int)(packed8[(size_t)sh * SH_STRIDE + idx] >> 32);
                v += cs[sh];
            }
        }
        s[threadIdx.x] = v;
        __syncthreads();
        for (int o = 1; o < 256; o <<= 1) {
            int t = 0;
            if (threadIdx.x >= o) t = s[threadIdx.x - o];
            __syncthreads();
            s[threadIdx.x] += t;
            __syncthreads();
        }
        if (idx < N_NODES) {
            int ex = boff[blockIdx.x] + s[threadIdx.x] - v;
            row_start[idx] = ex;
            int run = ex;
            #pragma unroll
            for (int sh = 0; sh < NSH; ++sh) {
                soff[(size_t)sh * SH_STRIDE + idx] = run;
                run += cs[sh];
            }
        }
    }
    grid.sync();

    // ---- phase D: fill CSR (grid-stride, atomic-free) ----
    const int stride = gridDim.x * 256;
    for (int e = tid; e < N_EDGES; e += stride) {
        int d = __builtin_nontemporal_load(&dst[e]);
        int sv = __builtin_nontemporal_load(&src[e]);
        float w = __builtin_nontemporal_load(&ew[e]);
        unsigned p16 = (unsigned)__builtin_nontemporal_load(&pos16[e]);
        int sh = (int)(p16 >> 12);
        int p  = (int)(p16 & 0xFFFu);
        float coef = dinv[sv] * w * dinv[d];
        csr[soff[(size_t)sh * SH_STRIDE + d] + p] = ((unsigned)sv << 16) | __half_as_ushort(__float2half(coef));
    }
}

// ---------- CSR aggregation: 32 lanes/node, chunk-major blocks, 2-deep pipeline ----------
template<int NP, bool HOUT>
__global__ void agg_csr_pair(const int* __restrict__ row_start, const unsigned* __restrict__ csr,
                             const __half* __restrict__ xwh, const float* __restrict__ dinv,
                             const float* __restrict__ b, void* __restrict__ outp) {
    constexpr int OUT = NP * 32;
    const int c    = blockIdx.x / NBLK8;
    const int nb   = blockIdx.x % NBLK8;
    const int n    = nb * 8 + (threadIdx.x >> 5);
    const int kk   = threadIdx.x & 15;
    const int half = (threadIdx.x >> 4) & 1;
    if (n >= N_NODES) return;
    const __half* __restrict__ bp = xwh + ((size_t)c * N_NODES) * 32 + 2 * kk;
    const int beg = row_start[n], end = row_start[n + 1];
    float ax = 0.f, ay = 0.f;
    int i = beg + half;
    unsigned ca0 = 0, ca1 = 0, ca2 = 0, ca3 = 0;
    unsigned cb0 = 0, cb1 = 0, cb2 = 0, cb3 = 0;
    __half2 ha0{}, ha1{}, ha2{}, ha3{};
    if (i + 6 < end) {
        ca0 = csr[i]; ca1 = csr[i + 2]; ca2 = csr[i + 4]; ca3 = csr[i + 6];
        ha0 = *(const __half2*)(bp + (size_t)(ca0 >> 16) * 32);
        ha1 = *(const __half2*)(bp + (size_t)(ca1 >> 16) * 32);
        ha2 = *(const __half2*)(bp + (size_t)(ca2 >> 16) * 32);
        ha3 = *(const __half2*)(bp + (size_t)(ca3 >> 16) * 32);
        int i2 = i + 8;
        if (i2 + 6 < end) { cb0 = csr[i2]; cb1 = csr[i2 + 2]; cb2 = csr[i2 + 4]; cb3 = csr[i2 + 6]; }
    }
    while (i + 6 < end) {
        int i2 = i + 8;
        // issue gathers for next batch (index 0 if dummy — harmless)
        __half2 hb0 = *(const __half2*)(bp + (size_t)(cb0 >> 16) * 32);
        __half2 hb1 = *(const __half2*)(bp + (size_t)(cb1 >> 16) * 32);
        __half2 hb2 = *(const __half2*)(bp + (size_t)(cb2 >> 16) * 32);
        __half2 hb3 = *(const __half2*)(bp + (size_t)(cb3 >> 16) * 32);
        // prefetch csr two batches ahead
        int i3 = i2 + 8;
        unsigned cc0 = 0, cc1 = 0, cc2 = 0, cc3 = 0;
        if (i3 + 6 < end) { cc0 = csr[i3]; cc1 = csr[i3 + 2]; cc2 = csr[i3 + 4]; cc3 = csr[i3 + 6]; }
        // consume current batch
        float2 f0 = __half22float2(ha0), f1 = __half22float2(ha1);
        float2 f2 = __half22float2(ha2), f3 = __half22float2(ha3);
        float e0 = coef_of(ca0), e1 = coef_of(ca1), e2 = coef_of(ca2), e3 = coef_of(ca3);
        ax += e0 * f0.x + e1 * f1.x + e2 * f2.x + e3 * f3.x;
        ay += e0 * f0.y + e1 * f1.y + e2 * f2.y + e3 * f3.y;
        // rotate
        ca0 = cb0; ca1 = cb1; ca2 = cb2; ca3 = cb3;
        ha0 = hb0; ha1 = hb1; ha2 = hb2; ha3 = hb3;
        cb0 = cc0; cb1 = cc1; cb2 = cc2; cb3 = cc3;
        i = i2;
    }
    for (; i < end; i += 2) {
        unsigned p = csr[i];
        float2 f = __half22float2(*(const __half2*)(bp + (size_t)(p >> 16) * 32));
        float e = coef_of(p);
        ax += e * f.x; ay += e * f.y;
    }
    ax += __shfl_xor(ax, 16);
    ay += __shfl_xor(ay, 16);
    if (half == 0) {
        float2 sf = __half22float2(*(const __half2*)(bp + (size_t)n * 32));
        float dv = dinv[n];
        float dv2 = dv * dv;
        int kg = c * 32 + 2 * kk;
        float ox = fmaxf(ax + dv2 * sf.x + b[kg], 0.f);
        float oy = fmaxf(ay + dv2 * sf.y + b[kg + 1], 0.f);
        if constexpr (HOUT) {
            __half* o = (__half*)outp;
            *(__half2*)&o[(size_t)n * OUT + kg] = __floats2half2_rn(ox, oy);
        } else {
            float* o = (float*)outp;
            *(float2*)&o[(size_t)n * OUT + kg] = make_float2(ox, oy);
        }
    }
}

// ---------- GEMM2: Yh(raw f16 pair-major [2][N][32]) = Xh(f16 [N,128]) @ W[128,64] ----------
__global__ void gemm2_reg(const __half* __restrict__ Xh, const float* __restrict__ W,
                          __half* __restrict__ Yh, int nrows) {
    __shared__ float Xl[32][132];
    __shared__ float Wl[128][64];
    const int rt = threadIdx.x >> 5;
    const int ct = threadIdx.x & 31;
    const int base = blockIdx.x * 32;
    for (int i = threadIdx.x; i < 32 * 32; i += 256) {
        int rr = i >> 5, cc = (i & 31) << 2;
        int gr = base + rr;
        float2 fa = make_float2(0.f, 0.f), fb = fa;
        if (gr < nrows) {
            const __half2* ph = (const __half2*)&Xh[(size_t)gr * 128 + cc];
            fa = __half22float2(ph[0]);
            fb = __half22float2(ph[1]);
        }
        Xl[rr][cc] = fa.x; Xl[rr][cc + 1] = fa.y; Xl[rr][cc + 2] = fb.x; Xl[rr][cc + 3] = fb.y;
    }
    for (int i = threadIdx.x; i < 128 * 16; i += 256) {
        int kk = i >> 4, cc = (i & 15) << 2;
        *(float4*)&Wl[kk][cc] = *(const float4*)&W[(size_t)kk * 64 + cc];
    }
    float acc[4][2] = {};
    __syncthreads();
    for (int k = 0; k < 128; k += 4) {
        float4 a0 = *(const float4*)&Xl[rt * 4 + 0][k];
        float4 a1 = *(const float4*)&Xl[rt * 4 + 1][k];
        float4 a2 = *(const float4*)&Xl[rt * 4 + 2][k];
        float4 a3 = *(const float4*)&Xl[rt * 4 + 3][k];
        float2 w0 = *(const float2*)&Wl[k + 0][ct * 2];
        float2 w1 = *(const float2*)&Wl[k + 1][ct * 2];
        float2 w2 = *(const float2*)&Wl[k + 2][ct * 2];
        float2 w3 = *(const float2*)&Wl[k + 3][ct * 2];
        acc[0][0] += a0.x * w0.x; acc[0][1] += a0.x * w0.y;
        acc[1][0] += a1.x * w0.x; acc[1][1] += a1.x * w0.y;
        acc[2][0] += a2.x * w0.x; acc[2][1] += a2.x * w0.y;
        acc[3][0] += a3.x * w0.x; acc[3][1] += a3.x * w0.y;
        acc[0][0] += a0.y * w1.x; acc[0][1] += a0.y * w1.y;
        acc[1][0] += a1.y * w1.x; acc[1][1] += a1.y * w1.y;
        acc[2][0] += a2.y * w1.x; acc[2][1] += a2.y * w1.y;
        acc[3][0] += a3.y * w1.x; acc[3][1] += a3.y * w1.y;
        acc[0][0] += a0.z * w2.x; acc[0][1] += a0.z * w2.y;
        acc[1][0] += a1.z * w2.x; acc[1][1] += a1.z * w2.y;
        acc[2][0] += a2.z * w2.x; acc[2][1] += a2.z * w2.y;
        acc[3][0] += a3.z * w2.x; acc[3][1] += a3.z * w2.y;
        acc[0][0] += a0.w * w3.x; acc[0][1] += a0.w * w3.y;
        acc[1][0] += a1.w * w3.x; acc[1][1] += a1.w * w3.y;
        acc[2][0] += a2.w * w3.x; acc[2][1] += a2.w * w3.y;
        acc[3][0] += a3.w * w3.x; acc[3][1] += a3.w * w3.y;
    }
    const int col0 = ct * 2;
    const int pc   = col0 >> 5;
    const int cw   = col0 & 31;
    for (int i = 0; i < 4; ++i) {
        int gr = base + rt * 4 + i;
        if (gr < nrows) {
            __half2 hv = __floats2half2_rn(acc[i][0], acc[i][1]);
            *(__half2*)&Yh[((size_t)pc * nrows + gr) * 32 + cw] = hv;
        }
    }
}

// ---------- fused gate + exp + pool, x1 staged in LDS ----------
__global__ void gate_pool(const __half* __restrict__ x1h, const float* __restrict__ gW1,
                          const float* __restrict__ gb1, const float* __restrict__ gW2,
                          const float* __restrict__ gb2, const int* __restrict__ batch,
                          float* __restrict__ den, float* __restrict__ pooledU) {
    __shared__ float W1l[64 * 32];
    __shared__ float W2l[32];
    __shared__ float b1l[32];
    __shared__ float Xs[256][65];
    __shared__ float el[256];
    for (int i = threadIdx.x; i < 64 * 32; i += 256) W1l[i] = gW1[i];
    if (threadIdx.x < 32) { W2l[threadIdx.x] = gW2[threadIdx.x]; b1l[threadIdx.x] = gb1[threadIdx.x]; }
    const int n0 = blockIdx.x * 256;
    for (int i = threadIdx.x; i < 256 * 16; i += 256) {
        int r = i >> 4, c4 = (i & 15) << 2;
        int nn = n0 + r;
        if (nn < N_NODES) {
            ushort4 u = *(const ushort4*)&x1h[(size_t)nn * 64 + c4];
            Xs[r][c4 + 0] = __half2float(__ushort_as_half(u.x));
            Xs[r][c4 + 1] = __half2float(__ushort_as_half(u.y));
            Xs[r][c4 + 2] = __half2float(__ushort_as_half(u.z));
            Xs[r][c4 + 3] = __half2float(__ushort_as_half(u.w));
        } else {
            Xs[r][c4 + 0] = 0.f; Xs[r][c4 + 1] = 0.f;
            Xs[r][c4 + 2] = 0.f; Xs[r][c4 + 3] = 0.f;
        }
    }
    __syncthreads();
    const float gb2v = gb2[0];
    const int n = n0 + threadIdx.x;
    float ev = 0.f;
    if (n < N_NODES) {
        float t[32];
        #pragma unroll
        for (int j = 0; j < 32; ++j) t[j] = b1l[j];
        for (int k = 0; k < 64; ++k) {
            float xv = Xs[threadIdx.x][k];
            #pragma unroll
            for (int j = 0; j < 32; ++j) t[j] += xv * W1l[k * 32 + j];
        }
        float a = gb2v;
        #pragma unroll
        for (int j = 0; j < 32; ++j) a += fmaxf(t[j], 0.f) * W2l[j];
        ev = expf(a);
    }
    el[threadIdx.x] = ev;
    __syncthreads();
    const int f   = threadIdx.x & 63;
    const int grp = threadIdx.x >> 6;
    int start = n0 + grp * 64;
    if (start >= N_NODES) return;
    int end = min(start + 64, N_NODES);
    int cur = batch[start];
    float acc = 0.f, accd = 0.f;
    for (int m = start; m < end; ++m) {
        int bb = batch[m];
        if (bb != cur) {
            atomicAdd(&pooledU[cur * 64 + f], acc);
            if (f == 0) atomicAdd(&den[cur], accd);
            acc = 0.f; accd = 0.f; cur = bb;
        }
        float e = el[m - n0];
        acc += e * Xs[m - n0][f];
        if (f == 0) accd += e;
    }
    atomicAdd(&pooledU[cur * 64 + f], acc);
    if (f == 0) atomicAdd(&den[cur], accd);
}

// ---------- head: one block per graph ----------
__global__ void head_kernel(const float* __restrict__ pooledU, const float* __restrict__ den,
                            const float* __restrict__ fcW1, const float* __restrict__ fcb1,
                            const float* __restrict__ fcW2, const float* __restrict__ fcb2,
                            float* __restrict__ out) {
    __shared__ float P[64];
    __shared__ float r0[2], r1[2];
    const int gi = blockIdx.x;
    if (threadIdx.x < 64) P[threadIdx.x] = pooledU[gi * 64 + threadIdx.x] / den[gi];
    __syncthreads();
    const int j = threadIdx.x;
    float a = fcb1[j];
    #pragma unroll 8
    for (int k = 0; k < 64; ++k) a += P[k] * fcW1[k * 128 + j];
    float h = fmaxf(a, 0.f);
    float p0 = h * fcW2[j * 2 + 0];
    float p1 = h * fcW2[j * 2 + 1];
    for (int o = 32; o; o >>= 1) { p0 += __shfl_xor(p0, o); p1 += __shfl_xor(p1, o); }
    if ((threadIdx.x & 63) == 0) { r0[threadIdx.x >> 6] = p0; r1[threadIdx.x >> 6] = p1; }
    __syncthreads();
    if (threadIdx.x == 0) {
        float l0 = r0[0] + r0[1] + fcb2[0];
        float l1 = r1[0] + r1[1] + fcb2[1];
        float m = fmaxf(l0, l1);
        float lse = m + logf(expf(l0 - m) + expf(l1 - m));
        out[gi * 2 + 0] = l0 - lse;
        out[gi * 2 + 1] = l1 - lse;
    }
}

extern "C" void kernel_launch(void* const* d_in, const int* in_sizes, int n_in,
                              void* d_out, int out_size, void* d_ws, size_t ws_size,
                              hipStream_t stream) {
    const float* x    = (const float*)d_in[0];
    const int*   ei   = (const int*)d_in[1];
    const float* ew   = (const float*)d_in[2];
    const int*   batch= (const int*)d_in[3];
    const float* W1   = (const float*)d_in[4];
    const float* b1   = (const float*)d_in[5];
    const float* W2   = (const float*)d_in[6];
    const float* b2   = (const float*)d_in[7];
    const float* gW1  = (const float*)d_in[8];
    const float* gb1  = (const float*)d_in[9];
    const float* gW2  = (const float*)d_in[10];
    const float* gb2  = (const float*)d_in[11];
    const float* fcW1 = (const float*)d_in[12];
    const float* fcb1 = (const float*)d_in[13];
    const float* fcW2 = (const float*)d_in[14];
    const float* fcb2 = (const float*)d_in[15];
    float* out = (float*)d_out;

    const int* src = ei;
    const int* dst = ei + N_EDGES;

    const int EB = (N_EDGES + 255) / 256;          // 6250
    const int NB = (N_NODES + 255) / 256;          // 196

    // ---- workspace layout (floats) ----
    float* ws = (float*)d_ws;
    __half* xwh  = (__half*)ws;                    // raw f16 pair-major [NP][N][32]
    __half* hbuf = (__half*)(ws + 3200000);        // h f16 [N][128]
    __half* x1h  = (__half*)(ws + 6400000);        // x1 f16 [N][64]
    size_t off = 9600000;
    unsigned* csr   = (unsigned*)(ws + off); off += 1600000;
    unsigned short* pos16 = (unsigned short*)(ws + off); off += 800000;
    int*   row_start= (int*)(ws + off);    off += 50176;
    unsigned long long* packed8 = (unsigned long long*)(ws + off); off += 2 * NSH * SH_STRIDE;
    int*   soff     = (int*)(ws + off);    off += NSH * SH_STRIDE;
    float* dinv     = ws + off;            off += 50176;
    int*   bsum     = (int*)(ws + off);    off += 256;
    int*   boff     = (int*)(ws + off);    off += 256;
    float* den      = ws + off;            off += 64;
    float* pooled   = ws + off;            off += 4096;

    // ---- memset (hist shards only; den+pooled zeroed inside coop kernel) ----
    hipMemsetAsync(packed8, 0, (size_t)NSH * SH_STRIDE * sizeof(unsigned long long), stream);

    // ---- phase 1: gemm1 (raw f16) co-dispatched with sharded packed hist ----
    mega1<<<G1BLKS + EB, 256, 0, stream>>>(x, W1, xwh, dst, ew, packed8, pos16);

    // ---- CSR finish: one cooperative kernel (dinv/bsum -> boff -> row_start/soff -> fill) ----
    {
        void* cargs[] = { (void*)&packed8, (void*)&src, (void*)&dst, (void*)&ew, (void*)&pos16,
                          (void*)&bsum, (void*)&boff, (void*)&row_start, (void*)&soff,
                          (void*)&dinv, (void*)&csr, (void*)&den };
        hipLaunchCooperativeKernel((void*)csr_build_coop, dim3(COOP_BLKS), dim3(256),
                                   cargs, 0, stream);
    }

    // ---- conv1 agg -> h (f16 [N][128]) ----
    agg_csr_pair<4, true><<<4 * NBLK8, 256, 0, stream>>>(row_start, csr, xwh, dinv, b1, hbuf);

    // ---- conv2 ----
    gemm2_reg<<<(N_NODES + 31) / 32, 256, 0, stream>>>(hbuf, W2, xwh, N_NODES);
    agg_csr_pair<2, true><<<2 * NBLK8, 256, 0, stream>>>(row_start, csr, xwh, dinv, b2, x1h);

    // ---- fused gate + exp + pool ----
    gate_pool<<<NB, 256, 0, stream>>>(x1h, gW1, gb1, gW2, gb2, batch, den, pooled);

    // ---- head (64 blocks) ----
    head_kernel<<<N_GRAPHS, 128, 0, stream>>>(pooled, den, fcW1, fcb1, fcW2, fcb2, out);
}

// Round 16
// 300.363 us; speedup vs baseline: 2.1393x; 2.1393x over previous
//
#include <hip/hip_runtime.h>
#include <hip/hip_bf16.h>
#include <hip/hip_fp16.h>

#define N_NODES 50000
#define N_EDGES 1600000
#define N_GRAPHS 64
#define G1BLKS 1563            // ceil(N_NODES/32) gemm1 blocks in mega kernel
#define NSH 8                  // histogram shards
#define SH_STRIDE 50048        // per-shard stride (≥ N_NODES, 64B aligned)
#define NBLK8 6250             // ceil(N_NODES/8) node-blocks for agg

// ---------- helpers ----------
__device__ __forceinline__ float coef_of(unsigned p) {
    return __half2float(__ushort_as_half((unsigned short)(p & 0xFFFFu)));
}

// ---------- MEGA: blocks [0,G1BLKS) = gemm1 (raw f16 out); rest = sharded packed hist ----------
__global__ void mega1(const float* __restrict__ X, const float* __restrict__ W,
                      __half* __restrict__ Yh, const int* __restrict__ dst,
                      const float* __restrict__ ew,
                      unsigned long long* __restrict__ packed8,
                      unsigned short* __restrict__ pos16) {
    __shared__ float Xl[32][132];
    if (blockIdx.x >= G1BLKS) {
        const int sh = blockIdx.x & (NSH - 1);
        unsigned long long* __restrict__ pk = packed8 + (size_t)sh * SH_STRIDE;
        int e = (blockIdx.x - G1BLKS) * 256 + threadIdx.x;
        if (e < N_EDGES) {
            int d = __builtin_nontemporal_load(&dst[e]);
            float w = __builtin_nontemporal_load(&ew[e]);
            unsigned fix = (unsigned)(w * 16777216.0f);
            unsigned long long old = atomicAdd(&pk[d], 0x100000000ull | (unsigned long long)fix);
            pos16[e] = (unsigned short)((sh << 12) | (unsigned)(old >> 32));
        }
        return;
    }
    const int rt = threadIdx.x >> 5;
    const int ct = threadIdx.x & 31;
    const int base = blockIdx.x * 32;
    for (int i = threadIdx.x; i < 32 * 32; i += 256) {
        int rr = i >> 5, cc = (i & 31) << 2;
        int gr = base + rr;
        float4 v = (gr < N_NODES) ? *(const float4*)&X[(size_t)gr * 128 + cc]
                                  : make_float4(0.f, 0.f, 0.f, 0.f);
        Xl[rr][cc] = v.x; Xl[rr][cc + 1] = v.y; Xl[rr][cc + 2] = v.z; Xl[rr][cc + 3] = v.w;
    }
    __syncthreads();
    float acc[4][4] = {};
    for (int k = 0; k < 128; k += 4) {
        float4 a0 = *(const float4*)&Xl[rt * 4 + 0][k];
        float4 a1 = *(const float4*)&Xl[rt * 4 + 1][k];
        float4 a2 = *(const float4*)&Xl[rt * 4 + 2][k];
        float4 a3 = *(const float4*)&Xl[rt * 4 + 3][k];
        float4 w0 = *(const float4*)&W[(size_t)(k + 0) * 128 + ct * 4];
        float4 w1 = *(const float4*)&W[(size_t)(k + 1) * 128 + ct * 4];
        float4 w2 = *(const float4*)&W[(size_t)(k + 2) * 128 + ct * 4];
        float4 w3 = *(const float4*)&W[(size_t)(k + 3) * 128 + ct * 4];
        #define STEP(av, wv)  \
            acc[0][0] += av##0 * wv.x; acc[0][1] += av##0 * wv.y; acc[0][2] += av##0 * wv.z; acc[0][3] += av##0 * wv.w; \
            acc[1][0] += av##1 * wv.x; acc[1][1] += av##1 * wv.y; acc[1][2] += av##1 * wv.z; acc[1][3] += av##1 * wv.w; \
            acc[2][0] += av##2 * wv.x; acc[2][1] += av##2 * wv.y; acc[2][2] += av##2 * wv.z; acc[2][3] += av##2 * wv.w; \
            acc[3][0] += av##3 * wv.x; acc[3][1] += av##3 * wv.y; acc[3][2] += av##3 * wv.z; acc[3][3] += av##3 * wv.w;
        { float ax0=a0.x, ax1=a1.x, ax2=a2.x, ax3=a3.x; STEP(ax, w0) }
        { float ay0=a0.y, ay1=a1.y, ay2=a2.y, ay3=a3.y; STEP(ay, w1) }
        { float az0=a0.z, az1=a1.z, az2=a2.z, az3=a3.z; STEP(az, w2) }
        { float aw0=a0.w, aw1=a1.w, aw2=a2.w, aw3=a3.w; STEP(aw, w3) }
        #undef STEP
    }
    const int pc = ct >> 3;
    const int cw = (ct & 7) * 4;
    for (int i = 0; i < 4; ++i) {
        int gr = base + rt * 4 + i;
        if (gr < N_NODES) {
            ushort4 u;
            u.x = __half_as_ushort(__float2half(acc[i][0]));
            u.y = __half_as_ushort(__float2half(acc[i][1]));
            u.z = __half_as_ushort(__float2half(acc[i][2]));
            u.w = __half_as_ushort(__float2half(acc[i][3]));
            *(ushort4*)&Yh[((size_t)pc * N_NODES + gr) * 32 + cw] = u;
        }
    }
}

// ---------- block sums + dinv (sums 8 shards) ----------
__global__ void block_sums_dinv(const unsigned long long* __restrict__ packed8,
                                int* __restrict__ bsum, float* __restrict__ dinv) {
    __shared__ int s[256];
    int idx = blockIdx.x * 256 + threadIdx.x;
    int c = 0;
    if (idx < N_NODES) {
        unsigned long long csum = 0, fsum = 0;
        #pragma unroll
        for (int sh = 0; sh < NSH; ++sh) {
            unsigned long long p = packed8[(size_t)sh * SH_STRIDE + idx];
            csum += p >> 32;
            fsum += p & 0xFFFFFFFFull;
        }
        c = (int)csum;
        dinv[idx] = rsqrtf((float)fsum * (1.0f / 16777216.0f) + 1.0f);
    }
    s[threadIdx.x] = c;
    __syncthreads();
    for (int o = 128; o; o >>= 1) {
        if (threadIdx.x < o) s[threadIdx.x] += s[threadIdx.x + o];
        __syncthreads();
    }
    if (threadIdx.x == 0) bsum[blockIdx.x] = s[0];
}

__global__ void scan_bsums(const int* __restrict__ bsum, int* __restrict__ boff,
                           int nb, int* __restrict__ row_start_last) {
    __shared__ int s[256];
    int v = (threadIdx.x < nb) ? bsum[threadIdx.x] : 0;
    s[threadIdx.x] = v;
    __syncthreads();
    for (int o = 1; o < 256; o <<= 1) {
        int t = 0;
        if (threadIdx.x >= o) t = s[threadIdx.x - o];
        __syncthreads();
        s[threadIdx.x] += t;
        __syncthreads();
    }
    if (threadIdx.x < nb) boff[threadIdx.x] = s[threadIdx.x] - v;   // exclusive
    if (threadIdx.x == 0) *row_start_last = N_EDGES;
}

__global__ void scan_counts(const unsigned long long* __restrict__ packed8,
                            const int* __restrict__ boff, int* __restrict__ row_start,
                            int* __restrict__ soff) {
    __shared__ int s[256];
    int idx = blockIdx.x * 256 + threadIdx.x;
    int cs[NSH];
    int v = 0;
    if (idx < N_NODES) {
        #pragma unroll
        for (int sh = 0; sh < NSH; ++sh) {
            cs[sh] = (int)(packed8[(size_t)sh * SH_STRIDE + idx] >> 32);
            v += cs[sh];
        }
    }
    s[threadIdx.x] = v;
    __syncthreads();
    for (int o = 1; o < 256; o <<= 1) {
        int t = 0;
        if (threadIdx.x >= o) t = s[threadIdx.x - o];
        __syncthreads();
        s[threadIdx.x] += t;
        __syncthreads();
    }
    if (idx < N_NODES) {
        int ex = boff[blockIdx.x] + s[threadIdx.x] - v;
        row_start[idx] = ex;
        int run = ex;
        #pragma unroll
        for (int sh = 0; sh < NSH; ++sh) {
            soff[(size_t)sh * SH_STRIDE + idx] = run;
            run += cs[sh];
        }
    }
}

// ---------- fill CSR: atomic-free, coef = dinv[s]*ew*dinv[d] as f16 ----------
__global__ void fill_direct(const int* __restrict__ src, const int* __restrict__ dst,
                            const float* __restrict__ ew, const unsigned short* __restrict__ pos16,
                            const int* __restrict__ soff, const float* __restrict__ dinv,
                            unsigned* __restrict__ csr) {
    int e = blockIdx.x * 256 + threadIdx.x;
    if (e < N_EDGES) {
        int d = __builtin_nontemporal_load(&dst[e]);
        int s = __builtin_nontemporal_load(&src[e]);
        float w = __builtin_nontemporal_load(&ew[e]);
        unsigned p16 = (unsigned)__builtin_nontemporal_load(&pos16[e]);
        int sh = (int)(p16 >> 12);
        int p  = (int)(p16 & 0xFFFu);
        float coef = dinv[s] * w * dinv[d];
        csr[soff[(size_t)sh * SH_STRIDE + d] + p] = ((unsigned)s << 16) | __half_as_ushort(__float2half(coef));
    }
}

// ---------- CSR aggregation: 32 lanes/node, chunk-major blocks, 2-deep pipeline ----------
template<int NP, bool HOUT>
__global__ void agg_csr_pair(const int* __restrict__ row_start, const unsigned* __restrict__ csr,
                             const __half* __restrict__ xwh, const float* __restrict__ dinv,
                             const float* __restrict__ b, void* __restrict__ outp) {
    constexpr int OUT = NP * 32;
    const int c    = blockIdx.x / NBLK8;
    const int nb   = blockIdx.x % NBLK8;
    const int n    = nb * 8 + (threadIdx.x >> 5);
    const int kk   = threadIdx.x & 15;
    const int half = (threadIdx.x >> 4) & 1;
    if (n >= N_NODES) return;
    const __half* __restrict__ bp = xwh + ((size_t)c * N_NODES) * 32 + 2 * kk;
    const int beg = row_start[n], end = row_start[n + 1];
    float ax = 0.f, ay = 0.f;
    int i = beg + half;
    unsigned ca0 = 0, ca1 = 0, ca2 = 0, ca3 = 0;
    unsigned cb0 = 0, cb1 = 0, cb2 = 0, cb3 = 0;
    __half2 ha0{}, ha1{}, ha2{}, ha3{};
    if (i + 6 < end) {
        ca0 = csr[i]; ca1 = csr[i + 2]; ca2 = csr[i + 4]; ca3 = csr[i + 6];
        ha0 = *(const __half2*)(bp + (size_t)(ca0 >> 16) * 32);
        ha1 = *(const __half2*)(bp + (size_t)(ca1 >> 16) * 32);
        ha2 = *(const __half2*)(bp + (size_t)(ca2 >> 16) * 32);
        ha3 = *(const __half2*)(bp + (size_t)(ca3 >> 16) * 32);
        int i2 = i + 8;
        if (i2 + 6 < end) { cb0 = csr[i2]; cb1 = csr[i2 + 2]; cb2 = csr[i2 + 4]; cb3 = csr[i2 + 6]; }
    }
    while (i + 6 < end) {
        int i2 = i + 8;
        __half2 hb0 = *(const __half2*)(bp + (size_t)(cb0 >> 16) * 32);
        __half2 hb1 = *(const __half2*)(bp + (size_t)(cb1 >> 16) * 32);
        __half2 hb2 = *(const __half2*)(bp + (size_t)(cb2 >> 16) * 32);
        __half2 hb3 = *(const __half2*)(bp + (size_t)(cb3 >> 16) * 32);
        int i3 = i2 + 8;
        unsigned cc0 = 0, cc1 = 0, cc2 = 0, cc3 = 0;
        if (i3 + 6 < end) { cc0 = csr[i3]; cc1 = csr[i3 + 2]; cc2 = csr[i3 + 4]; cc3 = csr[i3 + 6]; }
        float2 f0 = __half22float2(ha0), f1 = __half22float2(ha1);
        float2 f2 = __half22float2(ha2), f3 = __half22float2(ha3);
        float e0 = coef_of(ca0), e1 = coef_of(ca1), e2 = coef_of(ca2), e3 = coef_of(ca3);
        ax += e0 * f0.x + e1 * f1.x + e2 * f2.x + e3 * f3.x;
        ay += e0 * f0.y + e1 * f1.y + e2 * f2.y + e3 * f3.y;
        ca0 = cb0; ca1 = cb1; ca2 = cb2; ca3 = cb3;
        ha0 = hb0; ha1 = hb1; ha2 = hb2; ha3 = hb3;
        cb0 = cc0; cb1 = cc1; cb2 = cc2; cb3 = cc3;
        i = i2;
    }
    for (; i < end; i += 2) {
        unsigned p = csr[i];
        float2 f = __half22float2(*(const __half2*)(bp + (size_t)(p >> 16) * 32));
        float e = coef_of(p);
        ax += e * f.x; ay += e * f.y;
    }
    ax += __shfl_xor(ax, 16);
    ay += __shfl_xor(ay, 16);
    if (half == 0) {
        float2 sf = __half22float2(*(const __half2*)(bp + (size_t)n * 32));
        float dv = dinv[n];
        float dv2 = dv * dv;
        int kg = c * 32 + 2 * kk;
        float ox = fmaxf(ax + dv2 * sf.x + b[kg], 0.f);
        float oy = fmaxf(ay + dv2 * sf.y + b[kg + 1], 0.f);
        if constexpr (HOUT) {
            __half* o = (__half*)outp;
            *(__half2*)&o[(size_t)n * OUT + kg] = __floats2half2_rn(ox, oy);
        } else {
            float* o = (float*)outp;
            *(float2*)&o[(size_t)n * OUT + kg] = make_float2(ox, oy);
        }
    }
}

// ---------- GEMM2: Yh(raw f16 pair-major [2][N][32]) = Xh(f16 [N,128]) @ W[128,64] ----------
__global__ void gemm2_reg(const __half* __restrict__ Xh, const float* __restrict__ W,
                          __half* __restrict__ Yh, int nrows) {
    __shared__ float Xl[32][132];
    __shared__ float Wl[128][64];
    const int rt = threadIdx.x >> 5;
    const int ct = threadIdx.x & 31;
    const int base = blockIdx.x * 32;
    for (int i = threadIdx.x; i < 32 * 32; i += 256) {
        int rr = i >> 5, cc = (i & 31) << 2;
        int gr = base + rr;
        float2 fa = make_float2(0.f, 0.f), fb = fa;
        if (gr < nrows) {
            const __half2* ph = (const __half2*)&Xh[(size_t)gr * 128 + cc];
            fa = __half22float2(ph[0]);
            fb = __half22float2(ph[1]);
        }
        Xl[rr][cc] = fa.x; Xl[rr][cc + 1] = fa.y; Xl[rr][cc + 2] = fb.x; Xl[rr][cc + 3] = fb.y;
    }
    for (int i = threadIdx.x; i < 128 * 16; i += 256) {
        int kk = i >> 4, cc = (i & 15) << 2;
        *(float4*)&Wl[kk][cc] = *(const float4*)&W[(size_t)kk * 64 + cc];
    }
    float acc[4][2] = {};
    __syncthreads();
    for (int k = 0; k < 128; k += 4) {
        float4 a0 = *(const float4*)&Xl[rt * 4 + 0][k];
        float4 a1 = *(const float4*)&Xl[rt * 4 + 1][k];
        float4 a2 = *(const float4*)&Xl[rt * 4 + 2][k];
        float4 a3 = *(const float4*)&Xl[rt * 4 + 3][k];
        float2 w0 = *(const float2*)&Wl[k + 0][ct * 2];
        float2 w1 = *(const float2*)&Wl[k + 1][ct * 2];
        float2 w2 = *(const float2*)&Wl[k + 2][ct * 2];
        float2 w3 = *(const float2*)&Wl[k + 3][ct * 2];
        acc[0][0] += a0.x * w0.x; acc[0][1] += a0.x * w0.y;
        acc[1][0] += a1.x * w0.x; acc[1][1] += a1.x * w0.y;
        acc[2][0] += a2.x * w0.x; acc[2][1] += a2.x * w0.y;
        acc[3][0] += a3.x * w0.x; acc[3][1] += a3.x * w0.y;
        acc[0][0] += a0.y * w1.x; acc[0][1] += a0.y * w1.y;
        acc[1][0] += a1.y * w1.x; acc[1][1] += a1.y * w1.y;
        acc[2][0] += a2.y * w1.x; acc[2][1] += a2.y * w1.y;
        acc[3][0] += a3.y * w1.x; acc[3][1] += a3.y * w1.y;
        acc[0][0] += a0.z * w2.x; acc[0][1] += a0.z * w2.y;
        acc[1][0] += a1.z * w2.x; acc[1][1] += a1.z * w2.y;
        acc[2][0] += a2.z * w2.x; acc[2][1] += a2.z * w2.y;
        acc[3][0] += a3.z * w2.x; acc[3][1] += a3.z * w2.y;
        acc[0][0] += a0.w * w3.x; acc[0][1] += a0.w * w3.y;
        acc[1][0] += a1.w * w3.x; acc[1][1] += a1.w * w3.y;
        acc[2][0] += a2.w * w3.x; acc[2][1] += a2.w * w3.y;
        acc[3][0] += a3.w * w3.x; acc[3][1] += a3.w * w3.y;
    }
    const int col0 = ct * 2;
    const int pc   = col0 >> 5;
    const int cw   = col0 & 31;
    for (int i = 0; i < 4; ++i) {
        int gr = base + rt * 4 + i;
        if (gr < nrows) {
            __half2 hv = __floats2half2_rn(acc[i][0], acc[i][1]);
            *(__half2*)&Yh[((size_t)pc * nrows + gr) * 32 + cw] = hv;
        }
    }
}

// ---------- fused gate + exp + pool, x1 staged in LDS ----------
__global__ void gate_pool(const __half* __restrict__ x1h, const float* __restrict__ gW1,
                          const float* __restrict__ gb1, const float* __restrict__ gW2,
                          const float* __restrict__ gb2, const int* __restrict__ batch,
                          float* __restrict__ den, float* __restrict__ pooledU) {
    __shared__ float W1l[64 * 32];
    __shared__ float W2l[32];
    __shared__ float b1l[32];
    __shared__ float Xs[256][65];
    __shared__ float el[256];
    for (int i = threadIdx.x; i < 64 * 32; i += 256) W1l[i] = gW1[i];
    if (threadIdx.x < 32) { W2l[threadIdx.x] = gW2[threadIdx.x]; b1l[threadIdx.x] = gb1[threadIdx.x]; }
    const int n0 = blockIdx.x * 256;
    for (int i = threadIdx.x; i < 256 * 16; i += 256) {
        int r = i >> 4, c4 = (i & 15) << 2;
        int nn = n0 + r;
        if (nn < N_NODES) {
            ushort4 u = *(const ushort4*)&x1h[(size_t)nn * 64 + c4];
            Xs[r][c4 + 0] = __half2float(__ushort_as_half(u.x));
            Xs[r][c4 + 1] = __half2float(__ushort_as_half(u.y));
            Xs[r][c4 + 2] = __half2float(__ushort_as_half(u.z));
            Xs[r][c4 + 3] = __half2float(__ushort_as_half(u.w));
        } else {
            Xs[r][c4 + 0] = 0.f; Xs[r][c4 + 1] = 0.f;
            Xs[r][c4 + 2] = 0.f; Xs[r][c4 + 3] = 0.f;
        }
    }
    __syncthreads();
    const float gb2v = gb2[0];
    const int n = n0 + threadIdx.x;
    float ev = 0.f;
    if (n < N_NODES) {
        float t[32];
        #pragma unroll
        for (int j = 0; j < 32; ++j) t[j] = b1l[j];
        for (int k = 0; k < 64; ++k) {
            float xv = Xs[threadIdx.x][k];
            #pragma unroll
            for (int j = 0; j < 32; ++j) t[j] += xv * W1l[k * 32 + j];
        }
        float a = gb2v;
        #pragma unroll
        for (int j = 0; j < 32; ++j) a += fmaxf(t[j], 0.f) * W2l[j];
        ev = expf(a);
    }
    el[threadIdx.x] = ev;
    __syncthreads();
    const int f   = threadIdx.x & 63;
    const int grp = threadIdx.x >> 6;
    int start = n0 + grp * 64;
    if (start >= N_NODES) return;
    int end = min(start + 64, N_NODES);
    int cur = batch[start];
    float acc = 0.f, accd = 0.f;
    for (int m = start; m < end; ++m) {
        int bb = batch[m];
        if (bb != cur) {
            atomicAdd(&pooledU[cur * 64 + f], acc);
            if (f == 0) atomicAdd(&den[cur], accd);
            acc = 0.f; accd = 0.f; cur = bb;
        }
        float e = el[m - n0];
        acc += e * Xs[m - n0][f];
        if (f == 0) accd += e;
    }
    atomicAdd(&pooledU[cur * 64 + f], acc);
    if (f == 0) atomicAdd(&den[cur], accd);
}

// ---------- head: one block per graph ----------
__global__ void head_kernel(const float* __restrict__ pooledU, const float* __restrict__ den,
                            const float* __restrict__ fcW1, const float* __restrict__ fcb1,
                            const float* __restrict__ fcW2, const float* __restrict__ fcb2,
                            float* __restrict__ out) {
    __shared__ float P[64];
    __shared__ float r0[2], r1[2];
    const int gi = blockIdx.x;
    if (threadIdx.x < 64) P[threadIdx.x] = pooledU[gi * 64 + threadIdx.x] / den[gi];
    __syncthreads();
    const int j = threadIdx.x;
    float a = fcb1[j];
    #pragma unroll 8
    for (int k = 0; k < 64; ++k) a += P[k] * fcW1[k * 128 + j];
    float h = fmaxf(a, 0.f);
    float p0 = h * fcW2[j * 2 + 0];
    float p1 = h * fcW2[j * 2 + 1];
    for (int o = 32; o; o >>= 1) { p0 += __shfl_xor(p0, o); p1 += __shfl_xor(p1, o); }
    if ((threadIdx.x & 63) == 0) { r0[threadIdx.x >> 6] = p0; r1[threadIdx.x >> 6] = p1; }
    __syncthreads();
    if (threadIdx.x == 0) {
        float l0 = r0[0] + r0[1] + fcb2[0];
        float l1 = r1[0] + r1[1] + fcb2[1];
        float m = fmaxf(l0, l1);
        float lse = m + logf(expf(l0 - m) + expf(l1 - m));
        out[gi * 2 + 0] = l0 - lse;
        out[gi * 2 + 1] = l1 - lse;
    }
}

extern "C" void kernel_launch(void* const* d_in, const int* in_sizes, int n_in,
                              void* d_out, int out_size, void* d_ws, size_t ws_size,
                              hipStream_t stream) {
    const float* x    = (const float*)d_in[0];
    const int*   ei   = (const int*)d_in[1];
    const float* ew   = (const float*)d_in[2];
    const int*   batch= (const int*)d_in[3];
    const float* W1   = (const float*)d_in[4];
    const float* b1   = (const float*)d_in[5];
    const float* W2   = (const float*)d_in[6];
    const float* b2   = (const float*)d_in[7];
    const float* gW1  = (const float*)d_in[8];
    const float* gb1  = (const float*)d_in[9];
    const float* gW2  = (const float*)d_in[10];
    const float* gb2  = (const float*)d_in[11];
    const float* fcW1 = (const float*)d_in[12];
    const float* fcb1 = (const float*)d_in[13];
    const float* fcW2 = (const float*)d_in[14];
    const float* fcb2 = (const float*)d_in[15];
    float* out = (float*)d_out;

    const int* src = ei;
    const int* dst = ei + N_EDGES;

    const int EB = (N_EDGES + 255) / 256;          // 6250
    const int NB = (N_NODES + 255) / 256;          // 196

    // ---- workspace layout (floats) ----
    float* ws = (float*)d_ws;
    __half* xwh  = (__half*)ws;                    // raw f16 pair-major [NP][N][32]
    __half* hbuf = (__half*)(ws + 3200000);        // h f16 [N][128]
    __half* x1h  = (__half*)(ws + 6400000);        // x1 f16 [N][64]
    size_t off = 9600000;
    unsigned* csr   = (unsigned*)(ws + off); off += 1600000;
    unsigned short* pos16 = (unsigned short*)(ws + off); off += 800000;
    int*   row_start= (int*)(ws + off);    off += 50176;
    unsigned long long* packed8 = (unsigned long long*)(ws + off); off += 2 * NSH * SH_STRIDE;
    int*   soff     = (int*)(ws + off);    off += NSH * SH_STRIDE;
    float* dinv     = ws + off;            off += 50176;
    int*   bsum     = (int*)(ws + off);    off += 256;
    int*   boff     = (int*)(ws + off);    off += 256;
    float* den      = ws + off;            off += 64;
    float* pooled   = ws + off;            off += 4096;

    // ---- memsets ----
    hipMemsetAsync(packed8, 0, (size_t)NSH * SH_STRIDE * sizeof(unsigned long long), stream);
    hipMemsetAsync(den, 0, (64 + 4096) * sizeof(float), stream);

    // ---- phase 1: gemm1 (raw f16) co-dispatched with sharded packed hist ----
    mega1<<<G1BLKS + EB, 256, 0, stream>>>(x, W1, xwh, dst, ew, packed8, pos16);

    // ---- CSR finish (separate kernels — coop grid.sync proved 30x slower) ----
    block_sums_dinv<<<NB, 256, 0, stream>>>(packed8, bsum, dinv);
    scan_bsums<<<1, 256, 0, stream>>>(bsum, boff, NB, row_start + N_NODES);
    scan_counts<<<NB, 256, 0, stream>>>(packed8, boff, row_start, soff);
    fill_direct<<<EB, 256, 0, stream>>>(src, dst, ew, pos16, soff, dinv, csr);

    // ---- conv1 agg -> h (f16 [N][128]) ----
    agg_csr_pair<4, true><<<4 * NBLK8, 256, 0, stream>>>(row_start, csr, xwh, dinv, b1, hbuf);

    // ---- conv2 ----
    gemm2_reg<<<(N_NODES + 31) / 32, 256, 0, stream>>>(hbuf, W2, xwh, N_NODES);
    agg_csr_pair<2, true><<<2 * NBLK8, 256, 0, stream>>>(row_start, csr, xwh, dinv, b2, x1h);

    // ---- fused gate + exp + pool ----
    gate_pool<<<NB, 256, 0, stream>>>(x1h, gW1, gb1, gW2, gb2, batch, den, pooled);

    // ---- head (64 blocks) ----
    head_kernel<<<N_GRAPHS, 128, 0, stream>>>(pooled, den, fcW1, fcb1, fcW2, fcb2, out);
}

// Round 17
// 299.967 us; speedup vs baseline: 2.1421x; 1.0013x over previous
//
#include <hip/hip_runtime.h>
#include <hip/hip_bf16.h>
#include <hip/hip_fp16.h>

#define N_NODES 50000
#define N_EDGES 1600000
#define N_GRAPHS 64
#define G1BLKS 1563            // ceil(N_NODES/32) gemm1 blocks in mega kernel
#define NSH 8                  // histogram shards
#define SH_STRIDE 50048        // per-shard stride (≥ N_NODES, 64B aligned)
#define NBLK8 6250             // ceil(N_NODES/8) node-blocks for agg
#define SCAN_BLOCKS 196        // ceil(N_NODES/256), ≤ 256 CUs -> co-resident

// ---------- helpers ----------
__device__ __forceinline__ float coef_of(unsigned p) {
    return __half2float(__ushort_as_half((unsigned short)(p & 0xFFFFu)));
}

// ---------- MEGA: blocks [0,G1BLKS) = gemm1 (raw f16 out); rest = sharded packed hist ----------
__global__ void mega1(const float* __restrict__ X, const float* __restrict__ W,
                      __half* __restrict__ Yh, const int* __restrict__ dst,
                      const float* __restrict__ ew,
                      unsigned long long* __restrict__ packed8,
                      unsigned short* __restrict__ pos16) {
    __shared__ float Xl[32][132];
    if (blockIdx.x >= G1BLKS) {
        const int sh = blockIdx.x & (NSH - 1);
        unsigned long long* __restrict__ pk = packed8 + (size_t)sh * SH_STRIDE;
        int e = (blockIdx.x - G1BLKS) * 256 + threadIdx.x;
        if (e < N_EDGES) {
            int d = __builtin_nontemporal_load(&dst[e]);
            float w = __builtin_nontemporal_load(&ew[e]);
            unsigned fix = (unsigned)(w * 16777216.0f);
            unsigned long long old = atomicAdd(&pk[d], 0x100000000ull | (unsigned long long)fix);
            pos16[e] = (unsigned short)((sh << 12) | (unsigned)(old >> 32));
        }
        return;
    }
    const int rt = threadIdx.x >> 5;
    const int ct = threadIdx.x & 31;
    const int base = blockIdx.x * 32;
    for (int i = threadIdx.x; i < 32 * 32; i += 256) {
        int rr = i >> 5, cc = (i & 31) << 2;
        int gr = base + rr;
        float4 v = (gr < N_NODES) ? *(const float4*)&X[(size_t)gr * 128 + cc]
                                  : make_float4(0.f, 0.f, 0.f, 0.f);
        Xl[rr][cc] = v.x; Xl[rr][cc + 1] = v.y; Xl[rr][cc + 2] = v.z; Xl[rr][cc + 3] = v.w;
    }
    __syncthreads();
    float acc[4][4] = {};
    for (int k = 0; k < 128; k += 4) {
        float4 a0 = *(const float4*)&Xl[rt * 4 + 0][k];
        float4 a1 = *(const float4*)&Xl[rt * 4 + 1][k];
        float4 a2 = *(const float4*)&Xl[rt * 4 + 2][k];
        float4 a3 = *(const float4*)&Xl[rt * 4 + 3][k];
        float4 w0 = *(const float4*)&W[(size_t)(k + 0) * 128 + ct * 4];
        float4 w1 = *(const float4*)&W[(size_t)(k + 1) * 128 + ct * 4];
        float4 w2 = *(const float4*)&W[(size_t)(k + 2) * 128 + ct * 4];
        float4 w3 = *(const float4*)&W[(size_t)(k + 3) * 128 + ct * 4];
        #define STEP(av, wv)  \
            acc[0][0] += av##0 * wv.x; acc[0][1] += av##0 * wv.y; acc[0][2] += av##0 * wv.z; acc[0][3] += av##0 * wv.w; \
            acc[1][0] += av##1 * wv.x; acc[1][1] += av##1 * wv.y; acc[1][2] += av##1 * wv.z; acc[1][3] += av##1 * wv.w; \
            acc[2][0] += av##2 * wv.x; acc[2][1] += av##2 * wv.y; acc[2][2] += av##2 * wv.z; acc[2][3] += av##2 * wv.w; \
            acc[3][0] += av##3 * wv.x; acc[3][1] += av##3 * wv.y; acc[3][2] += av##3 * wv.z; acc[3][3] += av##3 * wv.w;
        { float ax0=a0.x, ax1=a1.x, ax2=a2.x, ax3=a3.x; STEP(ax, w0) }
        { float ay0=a0.y, ay1=a1.y, ay2=a2.y, ay3=a3.y; STEP(ay, w1) }
        { float az0=a0.z, az1=a1.z, az2=a2.z, az3=a3.z; STEP(az, w2) }
        { float aw0=a0.w, aw1=a1.w, aw2=a2.w, aw3=a3.w; STEP(aw, w3) }
        #undef STEP
    }
    const int pc = ct >> 3;
    const int cw = (ct & 7) * 4;
    for (int i = 0; i < 4; ++i) {
        int gr = base + rt * 4 + i;
        if (gr < N_NODES) {
            ushort4 u;
            u.x = __half_as_ushort(__float2half(acc[i][0]));
            u.y = __half_as_ushort(__float2half(acc[i][1]));
            u.z = __half_as_ushort(__float2half(acc[i][2]));
            u.w = __half_as_ushort(__float2half(acc[i][3]));
            *(ushort4*)&Yh[((size_t)pc * N_NODES + gr) * 32 + cw] = u;
        }
    }
}

// ---------- single-kernel scan (decoupled lookback): dinv + row_start + soff ----------
// 196 blocks (co-resident on 256 CUs). flags[] zeroed by host-side memset each call.
__global__ void scan_all(const unsigned long long* __restrict__ packed8,
                         float* __restrict__ dinv, int* __restrict__ row_start,
                         int* __restrict__ soff, int* __restrict__ flags,
                         int* __restrict__ totals) {
    __shared__ int s[256];
    const int idx = blockIdx.x * 256 + threadIdx.x;
    int cs[NSH];
    int v = 0;
    if (idx < N_NODES) {
        unsigned long long fsum = 0;
        #pragma unroll
        for (int sh = 0; sh < NSH; ++sh) {
            unsigned long long p = packed8[(size_t)sh * SH_STRIDE + idx];
            cs[sh] = (int)(p >> 32);
            v += cs[sh];
            fsum += p & 0xFFFFFFFFull;
        }
        dinv[idx] = rsqrtf((float)fsum * (1.0f / 16777216.0f) + 1.0f);
    } else {
        #pragma unroll
        for (int sh = 0; sh < NSH; ++sh) cs[sh] = 0;
    }
    s[threadIdx.x] = v;
    __syncthreads();
    for (int o = 1; o < 256; o <<= 1) {
        int t = 0;
        if (threadIdx.x >= o) t = s[threadIdx.x - o];
        __syncthreads();
        s[threadIdx.x] += t;
        __syncthreads();
    }
    const int inc = s[threadIdx.x];        // inclusive local prefix
    const int btotal = s[255];
    if (threadIdx.x == 0) {
        totals[blockIdx.x] = btotal;
        __threadfence();
        atomicExch(&flags[blockIdx.x], 1);
    }
    // lookback: thread t (< blockIdx) waits for block t's flag, reads its total
    int pre = 0;
    if ((int)threadIdx.x < (int)blockIdx.x) {
        while (atomicAdd(&flags[threadIdx.x], 0) == 0) {}
        pre = atomicAdd(&totals[threadIdx.x], 0);
    }
    __syncthreads();
    s[threadIdx.x] = pre;
    __syncthreads();
    for (int o = 128; o; o >>= 1) {
        if (threadIdx.x < o) s[threadIdx.x] += s[threadIdx.x + o];
        __syncthreads();
    }
    const int bpre = s[0];
    if (idx < N_NODES) {
        int ex = bpre + inc - v;
        row_start[idx] = ex;
        int run = ex;
        #pragma unroll
        for (int sh = 0; sh < NSH; ++sh) {
            soff[(size_t)sh * SH_STRIDE + idx] = run;
            run += cs[sh];
        }
    }
    if (blockIdx.x == SCAN_BLOCKS - 1 && threadIdx.x == 255) row_start[N_NODES] = N_EDGES;
}

// ---------- fill CSR: atomic-free, coef = dinv[s]*ew*dinv[d] as f16 ----------
__global__ void fill_direct(const int* __restrict__ src, const int* __restrict__ dst,
                            const float* __restrict__ ew, const unsigned short* __restrict__ pos16,
                            const int* __restrict__ soff, const float* __restrict__ dinv,
                            unsigned* __restrict__ csr) {
    int e = blockIdx.x * 256 + threadIdx.x;
    if (e < N_EDGES) {
        int d = __builtin_nontemporal_load(&dst[e]);
        int s = __builtin_nontemporal_load(&src[e]);
        float w = __builtin_nontemporal_load(&ew[e]);
        unsigned p16 = (unsigned)__builtin_nontemporal_load(&pos16[e]);
        int sh = (int)(p16 >> 12);
        int p  = (int)(p16 & 0xFFFu);
        float coef = dinv[s] * w * dinv[d];
        csr[soff[(size_t)sh * SH_STRIDE + d] + p] = ((unsigned)s << 16) | __half_as_ushort(__float2half(coef));
    }
}

// ---------- CSR aggregation: 32 lanes/node, chunk-major blocks, 1-deep pipeline (r14) ----------
template<int NP, bool HOUT>
__global__ void agg_csr_pair(const int* __restrict__ row_start, const unsigned* __restrict__ csr,
                             const __half* __restrict__ xwh, const float* __restrict__ dinv,
                             const float* __restrict__ b, void* __restrict__ outp) {
    constexpr int OUT = NP * 32;
    const int c    = blockIdx.x / NBLK8;
    const int nb   = blockIdx.x % NBLK8;
    const int n    = nb * 8 + (threadIdx.x >> 5);
    const int kk   = threadIdx.x & 15;
    const int half = (threadIdx.x >> 4) & 1;
    if (n >= N_NODES) return;
    const __half* __restrict__ bp = xwh + ((size_t)c * N_NODES) * 32 + 2 * kk;
    const int beg = row_start[n], end = row_start[n + 1];
    float ax = 0.f, ay = 0.f;
    int i = beg + half;
    unsigned c0 = 0, c1 = 0, c2 = 0, c3 = 0;
    if (i + 6 < end) { c0 = csr[i]; c1 = csr[i + 2]; c2 = csr[i + 4]; c3 = csr[i + 6]; }
    while (i + 6 < end) {
        __half2 h0 = *(const __half2*)(bp + (size_t)(c0 >> 16) * 32);
        __half2 h1 = *(const __half2*)(bp + (size_t)(c1 >> 16) * 32);
        __half2 h2 = *(const __half2*)(bp + (size_t)(c2 >> 16) * 32);
        __half2 h3 = *(const __half2*)(bp + (size_t)(c3 >> 16) * 32);
        float e0 = coef_of(c0), e1 = coef_of(c1), e2 = coef_of(c2), e3 = coef_of(c3);
        int ni = i + 8;
        unsigned d0 = 0, d1 = 0, d2 = 0, d3 = 0;
        if (ni + 6 < end) { d0 = csr[ni]; d1 = csr[ni + 2]; d2 = csr[ni + 4]; d3 = csr[ni + 6]; }
        float2 f0 = __half22float2(h0), f1 = __half22float2(h1);
        float2 f2 = __half22float2(h2), f3 = __half22float2(h3);
        ax += e0 * f0.x + e1 * f1.x + e2 * f2.x + e3 * f3.x;
        ay += e0 * f0.y + e1 * f1.y + e2 * f2.y + e3 * f3.y;
        c0 = d0; c1 = d1; c2 = d2; c3 = d3;
        i = ni;
    }
    for (; i < end; i += 2) {
        unsigned p = csr[i];
        float2 f = __half22float2(*(const __half2*)(bp + (size_t)(p >> 16) * 32));
        float e = coef_of(p);
        ax += e * f.x; ay += e * f.y;
    }
    ax += __shfl_xor(ax, 16);
    ay += __shfl_xor(ay, 16);
    if (half == 0) {
        float2 sf = __half22float2(*(const __half2*)(bp + (size_t)n * 32));
        float dv = dinv[n];
        float dv2 = dv * dv;
        int kg = c * 32 + 2 * kk;
        float ox = fmaxf(ax + dv2 * sf.x + b[kg], 0.f);
        float oy = fmaxf(ay + dv2 * sf.y + b[kg + 1], 0.f);
        if constexpr (HOUT) {
            __half* o = (__half*)outp;
            *(__half2*)&o[(size_t)n * OUT + kg] = __floats2half2_rn(ox, oy);
        } else {
            float* o = (float*)outp;
            *(float2*)&o[(size_t)n * OUT + kg] = make_float2(ox, oy);
        }
    }
}

// ---------- GEMM2: Yh(raw f16 pair-major [2][N][32]) = Xh(f16 [N,128]) @ W[128,64] ----------
__global__ void gemm2_reg(const __half* __restrict__ Xh, const float* __restrict__ W,
                          __half* __restrict__ Yh, int nrows) {
    __shared__ float Xl[32][132];
    __shared__ float Wl[128][64];
    const int rt = threadIdx.x >> 5;
    const int ct = threadIdx.x & 31;
    const int base = blockIdx.x * 32;
    for (int i = threadIdx.x; i < 32 * 32; i += 256) {
        int rr = i >> 5, cc = (i & 31) << 2;
        int gr = base + rr;
        float2 fa = make_float2(0.f, 0.f), fb = fa;
        if (gr < nrows) {
            const __half2* ph = (const __half2*)&Xh[(size_t)gr * 128 + cc];
            fa = __half22float2(ph[0]);
            fb = __half22float2(ph[1]);
        }
        Xl[rr][cc] = fa.x; Xl[rr][cc + 1] = fa.y; Xl[rr][cc + 2] = fb.x; Xl[rr][cc + 3] = fb.y;
    }
    for (int i = threadIdx.x; i < 128 * 16; i += 256) {
        int kk = i >> 4, cc = (i & 15) << 2;
        *(float4*)&Wl[kk][cc] = *(const float4*)&W[(size_t)kk * 64 + cc];
    }
    float acc[4][2] = {};
    __syncthreads();
    for (int k = 0; k < 128; k += 4) {
        float4 a0 = *(const float4*)&Xl[rt * 4 + 0][k];
        float4 a1 = *(const float4*)&Xl[rt * 4 + 1][k];
        float4 a2 = *(const float4*)&Xl[rt * 4 + 2][k];
        float4 a3 = *(const float4*)&Xl[rt * 4 + 3][k];
        float2 w0 = *(const float2*)&Wl[k + 0][ct * 2];
        float2 w1 = *(const float2*)&Wl[k + 1][ct * 2];
        float2 w2 = *(const float2*)&Wl[k + 2][ct * 2];
        float2 w3 = *(const float2*)&Wl[k + 3][ct * 2];
        acc[0][0] += a0.x * w0.x; acc[0][1] += a0.x * w0.y;
        acc[1][0] += a1.x * w0.x; acc[1][1] += a1.x * w0.y;
        acc[2][0] += a2.x * w0.x; acc[2][1] += a2.x * w0.y;
        acc[3][0] += a3.x * w0.x; acc[3][1] += a3.x * w0.y;
        acc[0][0] += a0.y * w1.x; acc[0][1] += a0.y * w1.y;
        acc[1][0] += a1.y * w1.x; acc[1][1] += a1.y * w1.y;
        acc[2][0] += a2.y * w1.x; acc[2][1] += a2.y * w1.y;
        acc[3][0] += a3.y * w1.x; acc[3][1] += a3.y * w1.y;
        acc[0][0] += a0.z * w2.x; acc[0][1] += a0.z * w2.y;
        acc[1][0] += a1.z * w2.x; acc[1][1] += a1.z * w2.y;
        acc[2][0] += a2.z * w2.x; acc[2][1] += a2.z * w2.y;
        acc[3][0] += a3.z * w2.x; acc[3][1] += a3.z * w2.y;
        acc[0][0] += a0.w * w3.x; acc[0][1] += a0.w * w3.y;
        acc[1][0] += a1.w * w3.x; acc[1][1] += a1.w * w3.y;
        acc[2][0] += a2.w * w3.x; acc[2][1] += a2.w * w3.y;
        acc[3][0] += a3.w * w3.x; acc[3][1] += a3.w * w3.y;
    }
    const int col0 = ct * 2;
    const int pc   = col0 >> 5;
    const int cw   = col0 & 31;
    for (int i = 0; i < 4; ++i) {
        int gr = base + rt * 4 + i;
        if (gr < nrows) {
            __half2 hv = __floats2half2_rn(acc[i][0], acc[i][1]);
            *(__half2*)&Yh[((size_t)pc * nrows + gr) * 32 + cw] = hv;
        }
    }
}

// ---------- fused gate + exp + pool, x1 staged in LDS ----------
__global__ void gate_pool(const __half* __restrict__ x1h, const float* __restrict__ gW1,
                          const float* __restrict__ gb1, const float* __restrict__ gW2,
                          const float* __restrict__ gb2, const int* __restrict__ batch,
                          float* __restrict__ den, float* __restrict__ pooledU) {
    __shared__ float W1l[64 * 32];
    __shared__ float W2l[32];
    __shared__ float b1l[32];
    __shared__ float Xs[256][65];
    __shared__ float el[256];
    for (int i = threadIdx.x; i < 64 * 32; i += 256) W1l[i] = gW1[i];
    if (threadIdx.x < 32) { W2l[threadIdx.x] = gW2[threadIdx.x]; b1l[threadIdx.x] = gb1[threadIdx.x]; }
    const int n0 = blockIdx.x * 256;
    for (int i = threadIdx.x; i < 256 * 16; i += 256) {
        int r = i >> 4, c4 = (i & 15) << 2;
        int nn = n0 + r;
        if (nn < N_NODES) {
            ushort4 u = *(const ushort4*)&x1h[(size_t)nn * 64 + c4];
            Xs[r][c4 + 0] = __half2float(__ushort_as_half(u.x));
            Xs[r][c4 + 1] = __half2float(__ushort_as_half(u.y));
            Xs[r][c4 + 2] = __half2float(__ushort_as_half(u.z));
            Xs[r][c4 + 3] = __half2float(__ushort_as_half(u.w));
        } else {
            Xs[r][c4 + 0] = 0.f; Xs[r][c4 + 1] = 0.f;
            Xs[r][c4 + 2] = 0.f; Xs[r][c4 + 3] = 0.f;
        }
    }
    __syncthreads();
    const float gb2v = gb2[0];
    const int n = n0 + threadIdx.x;
    float ev = 0.f;
    if (n < N_NODES) {
        float t[32];
        #pragma unroll
        for (int j = 0; j < 32; ++j) t[j] = b1l[j];
        for (int k = 0; k < 64; ++k) {
            float xv = Xs[threadIdx.x][k];
            #pragma unroll
            for (int j = 0; j < 32; ++j) t[j] += xv * W1l[k * 32 + j];
        }
        float a = gb2v;
        #pragma unroll
        for (int j = 0; j < 32; ++j) a += fmaxf(t[j], 0.f) * W2l[j];
        ev = expf(a);
    }
    el[threadIdx.x] = ev;
    __syncthreads();
    const int f   = threadIdx.x & 63;
    const int grp = threadIdx.x >> 6;
    int start = n0 + grp * 64;
    if (start >= N_NODES) return;
    int end = min(start + 64, N_NODES);
    int cur = batch[start];
    float acc = 0.f, accd = 0.f;
    for (int m = start; m < end; ++m) {
        int bb = batch[m];
        if (bb != cur) {
            atomicAdd(&pooledU[cur * 64 + f], acc);
            if (f == 0) atomicAdd(&den[cur], accd);
            acc = 0.f; accd = 0.f; cur = bb;
        }
        float e = el[m - n0];
        acc += e * Xs[m - n0][f];
        if (f == 0) accd += e;
    }
    atomicAdd(&pooledU[cur * 64 + f], acc);
    if (f == 0) atomicAdd(&den[cur], accd);
}

// ---------- head: one block per graph ----------
__global__ void head_kernel(const float* __restrict__ pooledU, const float* __restrict__ den,
                            const float* __restrict__ fcW1, const float* __restrict__ fcb1,
                            const float* __restrict__ fcW2, const float* __restrict__ fcb2,
                            float* __restrict__ out) {
    __shared__ float P[64];
    __shared__ float r0[2], r1[2];
    const int gi = blockIdx.x;
    if (threadIdx.x < 64) P[threadIdx.x] = pooledU[gi * 64 + threadIdx.x] / den[gi];
    __syncthreads();
    const int j = threadIdx.x;
    float a = fcb1[j];
    #pragma unroll 8
    for (int k = 0; k < 64; ++k) a += P[k] * fcW1[k * 128 + j];
    float h = fmaxf(a, 0.f);
    float p0 = h * fcW2[j * 2 + 0];
    float p1 = h * fcW2[j * 2 + 1];
    for (int o = 32; o; o >>= 1) { p0 += __shfl_xor(p0, o); p1 += __shfl_xor(p1, o); }
    if ((threadIdx.x & 63) == 0) { r0[threadIdx.x >> 6] = p0; r1[threadIdx.x >> 6] = p1; }
    __syncthreads();
    if (threadIdx.x == 0) {
        float l0 = r0[0] + r0[1] + fcb2[0];
        float l1 = r1[0] + r1[1] + fcb2[1];
        float m = fmaxf(l0, l1);
        float lse = m + logf(expf(l0 - m) + expf(l1 - m));
        out[gi * 2 + 0] = l0 - lse;
        out[gi * 2 + 1] = l1 - lse;
    }
}

extern "C" void kernel_launch(void* const* d_in, const int* in_sizes, int n_in,
                              void* d_out, int out_size, void* d_ws, size_t ws_size,
                              hipStream_t stream) {
    const float* x    = (const float*)d_in[0];
    const int*   ei   = (const int*)d_in[1];
    const float* ew   = (const float*)d_in[2];
    const int*   batch= (const int*)d_in[3];
    const float* W1   = (const float*)d_in[4];
    const float* b1   = (const float*)d_in[5];
    const float* W2   = (const float*)d_in[6];
    const float* b2   = (const float*)d_in[7];
    const float* gW1  = (const float*)d_in[8];
    const float* gb1  = (const float*)d_in[9];
    const float* gW2  = (const float*)d_in[10];
    const float* gb2  = (const float*)d_in[11];
    const float* fcW1 = (const float*)d_in[12];
    const float* fcb1 = (const float*)d_in[13];
    const float* fcW2 = (const float*)d_in[14];
    const float* fcb2 = (const float*)d_in[15];
    float* out = (float*)d_out;

    const int* src = ei;
    const int* dst = ei + N_EDGES;

    const int EB = (N_EDGES + 255) / 256;          // 6250
    const int NB = (N_NODES + 255) / 256;          // 196

    // ---- workspace layout (floats) ----
    float* ws = (float*)d_ws;
    __half* xwh  = (__half*)ws;                    // raw f16 pair-major [NP][N][32]
    __half* hbuf = (__half*)(ws + 3200000);        // h f16 [N][128]
    __half* x1h  = (__half*)(ws + 6400000);        // x1 f16 [N][64]
    size_t off = 9600000;
    unsigned* csr   = (unsigned*)(ws + off); off += 1600000;
    unsigned short* pos16 = (unsigned short*)(ws + off); off += 800000;
    int*   row_start= (int*)(ws + off);    off += 50176;
    unsigned long long* packed8 = (unsigned long long*)(ws + off); off += 2 * NSH * SH_STRIDE;
    int*   soff     = (int*)(ws + off);    off += NSH * SH_STRIDE;
    float* dinv     = ws + off;            off += 50176;
    float* den      = ws + off;            off += 64;
    float* pooled   = ws + off;            off += 4096;
    int*   flags    = (int*)(ws + off);    off += 256;   // zeroed with den/pooled
    int*   totals   = (int*)(ws + off);    off += 256;   // guarded by flags

    // ---- memsets (den|pooled|flags contiguous) ----
    hipMemsetAsync(packed8, 0, (size_t)NSH * SH_STRIDE * sizeof(unsigned long long), stream);
    hipMemsetAsync(den, 0, (64 + 4096 + 256) * sizeof(float), stream);

    // ---- phase 1: gemm1 (raw f16) co-dispatched with sharded packed hist ----
    mega1<<<G1BLKS + EB, 256, 0, stream>>>(x, W1, xwh, dst, ew, packed8, pos16);

    // ---- CSR scan: single decoupled-lookback kernel (dinv + row_start + soff) ----
    scan_all<<<SCAN_BLOCKS, 256, 0, stream>>>(packed8, dinv, row_start, soff, flags, totals);

    // ---- fill CSR ----
    fill_direct<<<EB, 256, 0, stream>>>(src, dst, ew, pos16, soff, dinv, csr);

    // ---- conv1 agg -> h (f16 [N][128]) ----
    agg_csr_pair<4, true><<<4 * NBLK8, 256, 0, stream>>>(row_start, csr, xwh, dinv, b1, hbuf);

    // ---- conv2 ----
    gemm2_reg<<<(N_NODES + 31) / 32, 256, 0, stream>>>(hbuf, W2, xwh, N_NODES);
    agg_csr_pair<2, true><<<2 * NBLK8, 256, 0, stream>>>(row_start, csr, xwh, dinv, b2, x1h);

    // ---- fused gate + exp + pool ----
    gate_pool<<<NB, 256, 0, stream>>>(x1h, gW1, gb1, gW2, gb2, batch, den, pooled);

    // ---- head (64 blocks) ----
    head_kernel<<<N_GRAPHS, 128, 0, stream>>>(pooled, den, fcW1, fcb1, fcW2, fcb2, out);
}